// Round 1
// baseline (5671.957 us; speedup 1.0000x reference)
//
#include <hip/hip_runtime.h>
#include <math.h>

// Problem: N=8192, D=512 (derived at runtime from in_sizes)
// Pipeline (re-associated for minimal FLOPs):
//   K  = tanh(U @ Wa^T + ba)            [N,D]   GEMM-NT + epi
//   L  = K @ H1^T                       [N,N]   GEMM-NT     (into d_out Xp region as scratch)
//   A2 = U * softmax_rows(L)            [N,N]   in-place
//   XW0= X @ W0                         [N,D]   GEMM-NN
//   T  = A2 @ XW0                       [N,D]   GEMM-NN     (into d_out Z region)
//   Z  = softmax_rows(T)                        in-place
//   UZ = U @ Z                          [N,D]   GEMM-NN
//   Xp = sigmoid(UZ @ W1)               [N,N]   GEMM-NN + epi

constexpr int BM = 128, BN = 128, BK = 8;

// EPI: 0=none, 1=tanh(x+bias[col]), 2=sigmoid
// TB : false -> B is [K,Ncol] row-major (NN); true -> B is [Ncol,K] row-major (NT)
template<int EPI, bool TB>
__global__ __launch_bounds__(256)
void gemm_f32(const float* __restrict__ A, const float* __restrict__ B,
              const float* __restrict__ bias, float* __restrict__ C,
              int M, int Ncol, int Kdim)
{
    __shared__ float As[BK][BM];
    __shared__ float Bs[BK][BN];
    const int t  = threadIdx.x;
    const int tx = t & 15, ty = t >> 4;
    const int m0 = blockIdx.y * BM, n0 = blockIdx.x * BN;

    const int arow  = t >> 1;        // 0..127
    const int acol4 = (t & 1) * 4;   // 0 or 4
    const int brow  = t >> 5;        // 0..7   (NN)
    const int bcol4 = (t & 31) * 4;  // 0..124 (NN)

    float acc[8][8];
#pragma unroll
    for (int i = 0; i < 8; ++i)
#pragma unroll
        for (int j = 0; j < 8; ++j) acc[i][j] = 0.f;

    const float* Aptr = A + (size_t)(m0 + arow) * Kdim + acol4;
    const float* Bptr;
    if (TB) Bptr = B + (size_t)(n0 + arow) * Kdim + acol4;
    else    Bptr = B + (size_t)brow * Ncol + n0 + bcol4;

    // register prefetch of first tile
    float4 av = *(const float4*)(Aptr);
    float4 bv = *(const float4*)(Bptr);

    for (int k0 = 0; k0 < Kdim; k0 += BK) {
        // stage current tile into LDS
        As[acol4 + 0][arow] = av.x;
        As[acol4 + 1][arow] = av.y;
        As[acol4 + 2][arow] = av.z;
        As[acol4 + 3][arow] = av.w;
        if (TB) {
            Bs[acol4 + 0][arow] = bv.x;
            Bs[acol4 + 1][arow] = bv.y;
            Bs[acol4 + 2][arow] = bv.z;
            Bs[acol4 + 3][arow] = bv.w;
        } else {
            *(float4*)&Bs[brow][bcol4] = bv;
        }
        __syncthreads();

        // prefetch next tile (hides HBM latency under the FMA block below)
        if (k0 + BK < Kdim) {
            av = *(const float4*)(Aptr + (k0 + BK));
            if (TB) bv = *(const float4*)(Bptr + (k0 + BK));
            else    bv = *(const float4*)(Bptr + (size_t)(k0 + BK) * Ncol);
        }

#pragma unroll
        for (int kk = 0; kk < BK; ++kk) {
            float a[8], b[8];
            *(float4*)&a[0] = *(const float4*)&As[kk][ty * 4];
            *(float4*)&a[4] = *(const float4*)&As[kk][64 + ty * 4];
            *(float4*)&b[0] = *(const float4*)&Bs[kk][tx * 4];
            *(float4*)&b[4] = *(const float4*)&Bs[kk][64 + tx * 4];
#pragma unroll
            for (int i = 0; i < 8; ++i)
#pragma unroll
                for (int j = 0; j < 8; ++j)
                    acc[i][j] = fmaf(a[i], b[j], acc[i][j]);
        }
        __syncthreads();
    }

    // epilogue
#pragma unroll
    for (int ib = 0; ib < 2; ++ib) {
#pragma unroll
        for (int ii = 0; ii < 4; ++ii) {
            const int i = ib * 4 + ii;
            const size_t row = (size_t)(m0 + ib * 64 + ty * 4 + ii);
            float* crow = C + row * (size_t)Ncol;
#pragma unroll
            for (int jb = 0; jb < 2; ++jb) {
                const int col0 = n0 + jb * 64 + tx * 4;
                float4 v;
                v.x = acc[i][jb * 4 + 0];
                v.y = acc[i][jb * 4 + 1];
                v.z = acc[i][jb * 4 + 2];
                v.w = acc[i][jb * 4 + 3];
                if (EPI == 1) {
                    v.x = tanhf(v.x + bias[col0 + 0]);
                    v.y = tanhf(v.y + bias[col0 + 1]);
                    v.z = tanhf(v.z + bias[col0 + 2]);
                    v.w = tanhf(v.w + bias[col0 + 3]);
                } else if (EPI == 2) {
                    v.x = 1.f / (1.f + __expf(-v.x));
                    v.y = 1.f / (1.f + __expf(-v.y));
                    v.z = 1.f / (1.f + __expf(-v.z));
                    v.w = 1.f / (1.f + __expf(-v.w));
                }
                *(float4*)(crow + col0) = v;
            }
        }
    }
}

__device__ inline float blockReduceMax(float v, float* sred)
{
    for (int o = 32; o > 0; o >>= 1) v = fmaxf(v, __shfl_down(v, o));
    const int lane = threadIdx.x & 63, wid = threadIdx.x >> 6;
    if (lane == 0) sred[wid] = v;
    __syncthreads();
    if (threadIdx.x == 0) {
        float m = sred[0];
        for (int w = 1; w < 4; ++w) m = fmaxf(m, sred[w]);
        sred[0] = m;
    }
    __syncthreads();
    float r = sred[0];
    __syncthreads();
    return r;
}

__device__ inline float blockReduceSum(float v, float* sred)
{
    for (int o = 32; o > 0; o >>= 1) v += __shfl_down(v, o);
    const int lane = threadIdx.x & 63, wid = threadIdx.x >> 6;
    if (lane == 0) sred[wid] = v;
    __syncthreads();
    if (threadIdx.x == 0) {
        float m = sred[0];
        for (int w = 1; w < 4; ++w) m += sred[w];
        sred[0] = m;
    }
    __syncthreads();
    float r = sred[0];
    __syncthreads();
    return r;
}

// One block per row. buf row (len Ncols=8192) -> A2 = U * softmax(row), in place.
__global__ __launch_bounds__(256)
void softmax_mul(float* buf, const float* __restrict__ U, int Ncols)
{
    __shared__ float srow[8192];
    __shared__ float sred[8];
    const int t = threadIdx.x;
    const size_t base = (size_t)blockIdx.x * Ncols;

    float lmax = -3.402823466e38f;
    for (int c = t * 4; c < Ncols; c += 1024) {
        float4 v = *(const float4*)(buf + base + c);
        *(float4*)&srow[c] = v;
        lmax = fmaxf(lmax, fmaxf(fmaxf(v.x, v.y), fmaxf(v.z, v.w)));
    }
    const float rmax = blockReduceMax(lmax, sred);

    float lsum = 0.f;
    for (int c = t * 4; c < Ncols; c += 1024) {
        float4 v = *(float4*)&srow[c];
        v.x = __expf(v.x - rmax);
        v.y = __expf(v.y - rmax);
        v.z = __expf(v.z - rmax);
        v.w = __expf(v.w - rmax);
        *(float4*)&srow[c] = v;
        lsum += v.x + v.y + v.z + v.w;
    }
    const float rsum = blockReduceSum(lsum, sred);
    const float inv = 1.f / rsum;

    for (int c = t * 4; c < Ncols; c += 1024) {
        float4 e = *(float4*)&srow[c];
        float4 u = *(const float4*)(U + base + c);
        float4 o;
        o.x = u.x * e.x * inv;
        o.y = u.y * e.y * inv;
        o.z = u.z * e.z * inv;
        o.w = u.w * e.w * inv;
        *(float4*)(buf + base + c) = o;
    }
}

// One block per row, D=512, in-place row softmax (2 elems/thread).
__global__ __launch_bounds__(256)
void softmax_inplace_small(float* buf, int D)
{
    __shared__ float sred[8];
    const int t = threadIdx.x;
    const size_t base = (size_t)blockIdx.x * D;
    float2 v = *(float2*)(buf + base + t * 2);
    const float rmax = blockReduceMax(fmaxf(v.x, v.y), sred);
    const float e0 = __expf(v.x - rmax);
    const float e1 = __expf(v.y - rmax);
    const float rsum = blockReduceSum(e0 + e1, sred);
    const float inv = 1.f / rsum;
    float2 o;
    o.x = e0 * inv;
    o.y = e1 * inv;
    *(float2*)(buf + base + t * 2) = o;
}

extern "C" void kernel_launch(void* const* d_in, const int* in_sizes, int n_in,
                              void* d_out, int out_size, void* d_ws, size_t ws_size,
                              hipStream_t stream)
{
    const float* U  = (const float*)d_in[0];
    const float* X  = (const float*)d_in[1];
    const float* H1 = (const float*)d_in[2];
    const float* W0 = (const float*)d_in[3];
    const float* W1 = (const float*)d_in[4];
    const float* Wa = (const float*)d_in[5];
    const float* ba = (const float*)d_in[6];
    const int D = in_sizes[6];
    const int N = (int)((long long)in_sizes[2] / D);

    float* Xp   = (float*)d_out;              // [N,N]; also scratch for L/A2
    float* Zp   = Xp + (size_t)N * N;         // [N,D]; also scratch for T
    float* bufA = (float*)d_ws;               // [N,D]: K, then XW0, then UZ

    dim3 blk(256);
    dim3 gD(D / BN, N / BM);   // (4, 64)
    dim3 gN(N / BN, N / BM);   // (64, 64)

    // 1) K = tanh(U @ Wa^T + ba) -> bufA
    hipLaunchKernelGGL((gemm_f32<1, true>),  gD, blk, 0, stream, U,    Wa, ba,      bufA, N, D, N);
    // 2) L = K @ H1^T -> Xp (scratch)
    hipLaunchKernelGGL((gemm_f32<0, true>),  gN, blk, 0, stream, bufA, H1, nullptr, Xp,   N, N, D);
    // 3) A2 = U * softmax_rows(L), in place on Xp
    hipLaunchKernelGGL(softmax_mul, dim3(N), blk, 0, stream, Xp, U, N);
    // 4) XW0 = X @ W0 -> bufA
    hipLaunchKernelGGL((gemm_f32<0, false>), gD, blk, 0, stream, X,    W0, nullptr, bufA, N, D, N);
    // 5) T = A2 @ XW0 -> Z region
    hipLaunchKernelGGL((gemm_f32<0, false>), gD, blk, 0, stream, Xp,   bufA, nullptr, Zp, N, D, N);
    // 6) Z = softmax_rows(T) in place
    hipLaunchKernelGGL(softmax_inplace_small, dim3(N), blk, 0, stream, Zp, D);
    // 7) UZ = U @ Z -> bufA
    hipLaunchKernelGGL((gemm_f32<0, false>), gD, blk, 0, stream, U,    Zp, nullptr, bufA, N, D, N);
    // 8) Xp = sigmoid(UZ @ W1) -> Xp
    hipLaunchKernelGGL((gemm_f32<2, false>), gN, blk, 0, stream, bufA, W1, nullptr, Xp,  N, N, D);
}

// Round 2
// 1873.992 us; speedup vs baseline: 3.0267x; 3.0267x over previous
//
#include <hip/hip_runtime.h>
#include <math.h>

// GCNNet: N=8192, D=512.
// K  = tanh(U @ Wa^T + ba)        [N,D]
// L  = K @ H1^T                   [N,N]
// A2 = U * softmax_rows(L)        [N,N]
// XW0= X @ W0                     [N,D]
// T  = A2 @ XW0                   [N,D]
// Z  = softmax_rows(T)
// UZ = U @ Z                      [N,D]
// Xp = sigmoid(UZ @ W1)           [N,N]
//
// MFMA path: fp32 -> bf16 (hi,lo) split; GEMM = 3 products (hi*hi + hi*lo + lo*hi)
// for precision-critical GEMMs, 1 product for the sigmoid-saturated tail GEMMs.

typedef __attribute__((ext_vector_type(8))) short bf16x8;
typedef __attribute__((ext_vector_type(4))) float f32x4;
typedef __attribute__((ext_vector_type(4))) unsigned short us4;

__device__ __forceinline__ unsigned short f2bf(float x) {
    unsigned int u = __float_as_uint(x);
    unsigned int r = (u + 0x7FFFu + ((u >> 16) & 1u)) >> 16;
    return (unsigned short)r;
}
__device__ __forceinline__ float bf2f(unsigned short h) {
    return __uint_as_float((unsigned int)h << 16);
}

__device__ __forceinline__ void gload_lds16(const char* g, char* l) {
    __builtin_amdgcn_global_load_lds(
        (const __attribute__((address_space(1))) unsigned int*)g,
        (__attribute__((address_space(3))) unsigned int*)l, 16, 0, 0);
}

// ---------------------------------------------------------------- converts
template<bool LO>
__global__ __launch_bounds__(256)
void convert_hilo(const float* __restrict__ in, unsigned short* __restrict__ hi,
                  unsigned short* __restrict__ lo, size_t n)
{
    size_t i = ((size_t)blockIdx.x * blockDim.x + threadIdx.x) * 4;
    const size_t stride = (size_t)gridDim.x * blockDim.x * 4;
    for (; i < n; i += stride) {
        float4 v = *(const float4*)(in + i);
        us4 h;
        h.x = f2bf(v.x); h.y = f2bf(v.y); h.z = f2bf(v.z); h.w = f2bf(v.w);
        *(us4*)(hi + i) = h;
        if (LO) {
            us4 l;
            l.x = f2bf(v.x - bf2f(h.x));
            l.y = f2bf(v.y - bf2f(h.y));
            l.z = f2bf(v.z - bf2f(h.z));
            l.w = f2bf(v.w - bf2f(h.w));
            *(us4*)(lo + i) = l;
        }
    }
}

// fp32 [R][C] -> bf16 hi/lo [C][R]
template<bool LO>
__global__ __launch_bounds__(256)
void transpose_convert(const float* __restrict__ in, unsigned short* __restrict__ hi,
                       unsigned short* __restrict__ lo, int R, int C)
{
    __shared__ float tile[32][33];
    const int t = threadIdx.x, tx = t & 31, ty = t >> 5;
    const int c0 = blockIdx.x * 32, r0 = blockIdx.y * 32;
#pragma unroll
    for (int i = 0; i < 4; ++i)
        tile[ty + 8 * i][tx] = in[(size_t)(r0 + ty + 8 * i) * C + c0 + tx];
    __syncthreads();
#pragma unroll
    for (int i = 0; i < 4; ++i) {
        float v = tile[tx][ty + 8 * i];
        size_t o = (size_t)(c0 + ty + 8 * i) * R + r0 + tx;
        unsigned short h = f2bf(v);
        hi[o] = h;
        if (LO) lo[o] = f2bf(v - bf2f(h));
    }
}

// ---------------------------------------------------------------- MFMA GEMM
// A: (hi[,lo]) bf16 row-major [M,Kdim]; B: (hi[,lo]) bf16 [Ncol,Kdim] (pre-transposed).
// FM: frags per wave in M (4 -> BM=128, 2 -> BM=64). BN=128 fixed.
// EPI: 0 = fp32 C; 1 = tanh(x+bias[col]) -> (Chi,Clo); 2 = sigmoid -> fp32 C; 3 = bf16 Chi.
template<int FM, int NPROD, int EPI>
__global__ __launch_bounds__(256)
void gemm_mfma(const unsigned short* __restrict__ Ahi, const unsigned short* __restrict__ Alo,
               const unsigned short* __restrict__ Bhi, const unsigned short* __restrict__ Blo,
               const float* __restrict__ bias, float* __restrict__ Cf,
               unsigned short* __restrict__ Chi, unsigned short* __restrict__ Clo,
               int M, int Ncol, int Kdim)
{
    constexpr bool SPLIT = (NPROD == 3);
    constexpr int BM = FM * 32;
    constexpr int BN = 128;
    constexpr int ABYTES = BM * 64;   // BM rows x 32 bf16 x 2B
    constexpr int BBYTES = BN * 64;
    constexpr int LDSB = (SPLIT ? 2 : 1) * (ABYTES + BBYTES);
    constexpr int CPW = LDSB / 1024 / 4;   // 1KB chunks per wave

    __shared__ __align__(1024) char lds[LDSB];

    const int t = threadIdx.x;
    const int w = t >> 6, lane = t & 63;
    const int m0 = blockIdx.y * BM, n0 = blockIdx.x * BN;
    const int wr = w >> 1, wc = w & 1;
    const int l15 = lane & 15, kq = lane >> 4;

    // staging assignment: linear LDS = [Ahi][Bhi][Alo][Blo], 16 rows of 64B per 1KB chunk
    const char* gsrc[CPW];
    char* lbase[CPW];
#pragma unroll
    for (int c = 0; c < CPW; ++c) {
        const int boff = (w * CPW + c) * 1024;
        lbase[c] = &lds[boff];
        const int poff = boff + lane * 16;
        const unsigned short* mat;
        int moff, rbase;
        if (poff < ABYTES)                     { mat = Ahi; moff = poff;                       rbase = m0; }
        else if (poff < ABYTES + BBYTES)       { mat = Bhi; moff = poff - ABYTES;              rbase = n0; }
        else if (poff < 2 * ABYTES + BBYTES)   { mat = Alo; moff = poff - ABYTES - BBYTES;     rbase = m0; }
        else                                   { mat = Blo; moff = poff - 2 * ABYTES - BBYTES; rbase = n0; }
        gsrc[c] = (const char*)(mat + (size_t)(rbase + (moff >> 6)) * Kdim) + (moff & 63);
    }

    int aoff[FM], boff_[4];
#pragma unroll
    for (int m = 0; m < FM; ++m)
        aoff[m] = (wr * (FM * 16) + m * 16 + l15) * 64 + kq * 16;
#pragma unroll
    for (int n = 0; n < 4; ++n)
        boff_[n] = (wc * 64 + n * 16 + l15) * 64 + kq * 16;

    f32x4 acc[FM][4];
#pragma unroll
    for (int m = 0; m < FM; ++m)
#pragma unroll
        for (int n = 0; n < 4; ++n)
            acc[m][n] = (f32x4)(0.f);

    const int ksteps = Kdim >> 5;
    for (int ks = 0; ks < ksteps; ++ks) {
#pragma unroll
        for (int c = 0; c < CPW; ++c) {
            gload_lds16(gsrc[c], lbase[c]);
            gsrc[c] += 64;   // advance 32 bf16 in K
        }
        __syncthreads();

        bf16x8 ah[FM], al[FM];
#pragma unroll
        for (int m = 0; m < FM; ++m) {
            ah[m] = *(const bf16x8*)(lds + aoff[m]);
            if constexpr (SPLIT)
                al[m] = *(const bf16x8*)(lds + ABYTES + BBYTES + aoff[m]);
        }
#pragma unroll
        for (int n = 0; n < 4; ++n) {
            bf16x8 bh = *(const bf16x8*)(lds + ABYTES + boff_[n]);
#pragma unroll
            for (int m = 0; m < FM; ++m)
                acc[m][n] = __builtin_amdgcn_mfma_f32_16x16x32_bf16(ah[m], bh, acc[m][n], 0, 0, 0);
            if constexpr (SPLIT) {
                bf16x8 bl = *(const bf16x8*)(lds + 2 * ABYTES + BBYTES + boff_[n]);
#pragma unroll
                for (int m = 0; m < FM; ++m) {
                    acc[m][n] = __builtin_amdgcn_mfma_f32_16x16x32_bf16(ah[m], bl, acc[m][n], 0, 0, 0);
                    acc[m][n] = __builtin_amdgcn_mfma_f32_16x16x32_bf16(al[m], bh, acc[m][n], 0, 0, 0);
                }
            }
        }
        __syncthreads();
    }

    // epilogue: C/D frag layout col=lane&15, row=(lane>>4)*4+r
#pragma unroll
    for (int m = 0; m < FM; ++m) {
        const int rowb = m0 + wr * (FM * 16) + m * 16 + kq * 4;
#pragma unroll
        for (int n = 0; n < 4; ++n) {
            const int col = n0 + wc * 64 + n * 16 + l15;
#pragma unroll
            for (int r = 0; r < 4; ++r) {
                float v = acc[m][n][r];
                const size_t idx = (size_t)(rowb + r) * Ncol + col;
                if constexpr (EPI == 0) {
                    Cf[idx] = v;
                } else if constexpr (EPI == 1) {
                    v = tanhf(v + bias[col]);
                    unsigned short h = f2bf(v);
                    Chi[idx] = h;
                    Clo[idx] = f2bf(v - bf2f(h));
                } else if constexpr (EPI == 2) {
                    Cf[idx] = 1.f / (1.f + __expf(-v));
                } else {
                    Chi[idx] = f2bf(v);
                }
            }
        }
    }
}

// ---------------------------------------------------------------- reductions
__device__ inline float blockReduceMax(float v, float* sred)
{
    for (int o = 32; o > 0; o >>= 1) v = fmaxf(v, __shfl_down(v, o));
    const int lane = threadIdx.x & 63, wid = threadIdx.x >> 6;
    if (lane == 0) sred[wid] = v;
    __syncthreads();
    if (threadIdx.x == 0) {
        float m = sred[0];
        for (int w = 1; w < 4; ++w) m = fmaxf(m, sred[w]);
        sred[0] = m;
    }
    __syncthreads();
    float r = sred[0];
    __syncthreads();
    return r;
}

__device__ inline float blockReduceSum(float v, float* sred)
{
    for (int o = 32; o > 0; o >>= 1) v += __shfl_down(v, o);
    const int lane = threadIdx.x & 63, wid = threadIdx.x >> 6;
    if (lane == 0) sred[wid] = v;
    __syncthreads();
    if (threadIdx.x == 0) {
        float m = sred[0];
        for (int w = 1; w < 4; ++w) m += sred[w];
        sred[0] = m;
    }
    __syncthreads();
    float r = sred[0];
    __syncthreads();
    return r;
}

// A2 = U * softmax_rows(L); write bf16 hi/lo (one block per row, Ncols=8192)
__global__ __launch_bounds__(256)
void softmax_mul_hilo(const float* __restrict__ Lrow, const float* __restrict__ U,
                      unsigned short* __restrict__ hi, unsigned short* __restrict__ lo,
                      int Ncols)
{
    __shared__ float srow[8192];
    __shared__ float sred[8];
    const int t = threadIdx.x;
    const size_t base = (size_t)blockIdx.x * Ncols;

    float lmax = -3.402823466e38f;
    for (int c = t * 4; c < Ncols; c += 1024) {
        float4 v = *(const float4*)(Lrow + base + c);
        *(float4*)&srow[c] = v;
        lmax = fmaxf(lmax, fmaxf(fmaxf(v.x, v.y), fmaxf(v.z, v.w)));
    }
    const float rmax = blockReduceMax(lmax, sred);

    float lsum = 0.f;
    for (int c = t * 4; c < Ncols; c += 1024) {
        float4 v = *(float4*)&srow[c];
        v.x = __expf(v.x - rmax);
        v.y = __expf(v.y - rmax);
        v.z = __expf(v.z - rmax);
        v.w = __expf(v.w - rmax);
        *(float4*)&srow[c] = v;
        lsum += v.x + v.y + v.z + v.w;
    }
    const float rsum = blockReduceSum(lsum, sred);
    const float inv = 1.f / rsum;

    for (int c = t * 4; c < Ncols; c += 1024) {
        float4 e = *(float4*)&srow[c];
        float4 u = *(const float4*)(U + base + c);
        float a0 = u.x * e.x * inv, a1 = u.y * e.y * inv;
        float a2 = u.z * e.z * inv, a3 = u.w * e.w * inv;
        us4 h, l;
        h.x = f2bf(a0); l.x = f2bf(a0 - bf2f(h.x));
        h.y = f2bf(a1); l.y = f2bf(a1 - bf2f(h.y));
        h.z = f2bf(a2); l.z = f2bf(a2 - bf2f(h.z));
        h.w = f2bf(a3); l.w = f2bf(a3 - bf2f(h.w));
        *(us4*)(hi + base + c) = h;
        *(us4*)(lo + base + c) = l;
    }
}

// in-place row softmax, D=512, one block per row
__global__ __launch_bounds__(256)
void softmax_inplace_small(float* buf, int D)
{
    __shared__ float sred[8];
    const int t = threadIdx.x;
    const size_t base = (size_t)blockIdx.x * D;
    float2 v = *(float2*)(buf + base + t * 2);
    const float rmax = blockReduceMax(fmaxf(v.x, v.y), sred);
    const float e0 = __expf(v.x - rmax);
    const float e1 = __expf(v.y - rmax);
    const float rsum = blockReduceSum(e0 + e1, sred);
    const float inv = 1.f / rsum;
    float2 o;
    o.x = e0 * inv;
    o.y = e1 * inv;
    *(float2*)(buf + base + t * 2) = o;
}

// ---------------------------------------------------------------- fp32 fallback GEMM
template<int EPI, bool TB>
__global__ __launch_bounds__(256)
void gemm_f32(const float* __restrict__ A, const float* __restrict__ B,
              const float* __restrict__ bias, float* __restrict__ C,
              int M, int Ncol, int Kdim)
{
    constexpr int FBM = 128, FBN = 128, FBK = 8;
    __shared__ float As[FBK][FBM];
    __shared__ float Bs[FBK][FBN];
    const int t  = threadIdx.x;
    const int tx = t & 15, ty = t >> 4;
    const int m0 = blockIdx.y * FBM, n0 = blockIdx.x * FBN;

    const int arow  = t >> 1;
    const int acol4 = (t & 1) * 4;
    const int brow  = t >> 5;
    const int bcol4 = (t & 31) * 4;

    float acc[8][8];
#pragma unroll
    for (int i = 0; i < 8; ++i)
#pragma unroll
        for (int j = 0; j < 8; ++j) acc[i][j] = 0.f;

    const float* Aptr = A + (size_t)(m0 + arow) * Kdim + acol4;
    const float* Bptr;
    if (TB) Bptr = B + (size_t)(n0 + arow) * Kdim + acol4;
    else    Bptr = B + (size_t)brow * Ncol + n0 + bcol4;

    float4 av = *(const float4*)(Aptr);
    float4 bv = *(const float4*)(Bptr);

    for (int k0 = 0; k0 < Kdim; k0 += FBK) {
        As[acol4 + 0][arow] = av.x;
        As[acol4 + 1][arow] = av.y;
        As[acol4 + 2][arow] = av.z;
        As[acol4 + 3][arow] = av.w;
        if (TB) {
            Bs[acol4 + 0][arow] = bv.x;
            Bs[acol4 + 1][arow] = bv.y;
            Bs[acol4 + 2][arow] = bv.z;
            Bs[acol4 + 3][arow] = bv.w;
        } else {
            *(float4*)&Bs[brow][bcol4] = bv;
        }
        __syncthreads();

        if (k0 + FBK < Kdim) {
            av = *(const float4*)(Aptr + (k0 + FBK));
            if (TB) bv = *(const float4*)(Bptr + (k0 + FBK));
            else    bv = *(const float4*)(Bptr + (size_t)(k0 + FBK) * Ncol);
        }

#pragma unroll
        for (int kk = 0; kk < FBK; ++kk) {
            float a[8], b[8];
            *(float4*)&a[0] = *(const float4*)&As[kk][ty * 4];
            *(float4*)&a[4] = *(const float4*)&As[kk][64 + ty * 4];
            *(float4*)&b[0] = *(const float4*)&Bs[kk][tx * 4];
            *(float4*)&b[4] = *(const float4*)&Bs[kk][64 + tx * 4];
#pragma unroll
            for (int i = 0; i < 8; ++i)
#pragma unroll
                for (int j = 0; j < 8; ++j)
                    acc[i][j] = fmaf(a[i], b[j], acc[i][j]);
        }
        __syncthreads();
    }

#pragma unroll
    for (int ib = 0; ib < 2; ++ib) {
#pragma unroll
        for (int ii = 0; ii < 4; ++ii) {
            const int i = ib * 4 + ii;
            const size_t row = (size_t)(m0 + ib * 64 + ty * 4 + ii);
            float* crow = C + row * (size_t)Ncol;
#pragma unroll
            for (int jb = 0; jb < 2; ++jb) {
                const int col0 = n0 + jb * 64 + tx * 4;
                float4 v;
                v.x = acc[i][jb * 4 + 0];
                v.y = acc[i][jb * 4 + 1];
                v.z = acc[i][jb * 4 + 2];
                v.w = acc[i][jb * 4 + 3];
                if (EPI == 1) {
                    v.x = tanhf(v.x + bias[col0 + 0]);
                    v.y = tanhf(v.y + bias[col0 + 1]);
                    v.z = tanhf(v.z + bias[col0 + 2]);
                    v.w = tanhf(v.w + bias[col0 + 3]);
                } else if (EPI == 2) {
                    v.x = 1.f / (1.f + __expf(-v.x));
                    v.y = 1.f / (1.f + __expf(-v.y));
                    v.z = 1.f / (1.f + __expf(-v.z));
                    v.w = 1.f / (1.f + __expf(-v.w));
                }
                *(float4*)(crow + col0) = v;
            }
        }
    }
}

__global__ __launch_bounds__(256)
void softmax_mul_f32(float* buf, const float* __restrict__ U, int Ncols)
{
    __shared__ float srow[8192];
    __shared__ float sred[8];
    const int t = threadIdx.x;
    const size_t base = (size_t)blockIdx.x * Ncols;

    float lmax = -3.402823466e38f;
    for (int c = t * 4; c < Ncols; c += 1024) {
        float4 v = *(const float4*)(buf + base + c);
        *(float4*)&srow[c] = v;
        lmax = fmaxf(lmax, fmaxf(fmaxf(v.x, v.y), fmaxf(v.z, v.w)));
    }
    const float rmax = blockReduceMax(lmax, sred);

    float lsum = 0.f;
    for (int c = t * 4; c < Ncols; c += 1024) {
        float4 v = *(float4*)&srow[c];
        v.x = __expf(v.x - rmax);
        v.y = __expf(v.y - rmax);
        v.z = __expf(v.z - rmax);
        v.w = __expf(v.w - rmax);
        *(float4*)&srow[c] = v;
        lsum += v.x + v.y + v.z + v.w;
    }
    const float rsum = blockReduceSum(lsum, sred);
    const float inv = 1.f / rsum;

    for (int c = t * 4; c < Ncols; c += 1024) {
        float4 e = *(float4*)&srow[c];
        float4 u = *(const float4*)(U + base + c);
        float4 o;
        o.x = u.x * e.x * inv;
        o.y = u.y * e.y * inv;
        o.z = u.z * e.z * inv;
        o.w = u.w * e.w * inv;
        *(float4*)(buf + base + c) = o;
    }
}

// ---------------------------------------------------------------- launch
extern "C" void kernel_launch(void* const* d_in, const int* in_sizes, int n_in,
                              void* d_out, int out_size, void* d_ws, size_t ws_size,
                              hipStream_t stream)
{
    const float* U  = (const float*)d_in[0];
    const float* X  = (const float*)d_in[1];
    const float* H1 = (const float*)d_in[2];
    const float* W0 = (const float*)d_in[3];
    const float* W1 = (const float*)d_in[4];
    const float* Wa = (const float*)d_in[5];
    const float* ba = (const float*)d_in[6];
    const int D = in_sizes[6];
    const int N = (int)((long long)in_sizes[2] / D);
    const size_t NN = (size_t)N * N, ND = (size_t)N * D;

    float* Xp = (float*)d_out;          // [N,N] final; also scratch for L
    float* Zp = Xp + NN;                // [N,D] final Z; also scratch for T

    // ---- workspace layout for MFMA path
    char* p = (char*)d_ws;
    auto alloc = [&](size_t bytes) { char* r = p; p += (bytes + 255) & ~(size_t)255; return r; };
    unsigned short* R1a   = (unsigned short*)alloc(NN * 2);   // Uhi / Xhi / A2hi / Uhi2
    unsigned short* R1b   = (unsigned short*)alloc(NN * 2);   // Ulo / Xlo / A2lo
    unsigned short* wahi  = (unsigned short*)alloc(ND * 2);
    unsigned short* walo  = (unsigned short*)alloc(ND * 2);
    unsigned short* h1hi  = (unsigned short*)alloc(ND * 2);
    unsigned short* h1lo  = (unsigned short*)alloc(ND * 2);
    unsigned short* khi   = (unsigned short*)alloc(ND * 2);
    unsigned short* klo   = (unsigned short*)alloc(ND * 2);
    unsigned short* w0thi = (unsigned short*)alloc(ND * 2);
    unsigned short* w0tlo = (unsigned short*)alloc(ND * 2);
    unsigned short* xw0thi= (unsigned short*)alloc(ND * 2);
    unsigned short* xw0tlo= (unsigned short*)alloc(ND * 2);
    unsigned short* zthi  = (unsigned short*)alloc(ND * 2);
    unsigned short* uzhi  = (unsigned short*)alloc(ND * 2);
    unsigned short* w1thi = (unsigned short*)alloc(ND * 2);
    float*          xw0f  = (float*)alloc(ND * 4);
    const size_t need = (size_t)(p - (char*)d_ws);

    dim3 blk(256);

    if (N == 8192 && D == 512 && ws_size >= need) {
        // -------- MFMA split-bf16 path
        const dim3 gSlim(D / 128, N / 64);    // (4,128) for [N,D]-output GEMMs
        const dim3 gBig(N / 128, N / 128);    // (64,64) for [N,N]-output GEMMs
        const dim3 gT(D / 32, N / 32);        // transpose [N,D] -> [D,N]
        const dim3 gTw1(N / 32, D / 32);      // transpose [D,N] -> [N,D]
        const int cgrid = 4096;

        // 1) U -> hi/lo
        hipLaunchKernelGGL((convert_hilo<true>), dim3(cgrid), blk, 0, stream, U, R1a, R1b, NN);
        hipLaunchKernelGGL((convert_hilo<true>), dim3(512),  blk, 0, stream, Wa, wahi, walo, ND);
        // K = tanh(U @ Wa^T + ba) -> khi/klo
        hipLaunchKernelGGL((gemm_mfma<2, 3, 1>), gSlim, blk, 0, stream,
                           R1a, R1b, wahi, walo, ba, (float*)nullptr, khi, klo, N, D, N);
        hipLaunchKernelGGL((convert_hilo<true>), dim3(512), blk, 0, stream, H1, h1hi, h1lo, ND);
        // L = K @ H1^T -> Xp
        hipLaunchKernelGGL((gemm_mfma<4, 3, 0>), gBig, blk, 0, stream,
                           khi, klo, h1hi, h1lo, (const float*)nullptr, Xp,
                           (unsigned short*)nullptr, (unsigned short*)nullptr, N, N, D);
        // X -> hi/lo (overwrites U hi/lo; U raw still in d_in)
        hipLaunchKernelGGL((convert_hilo<true>), dim3(cgrid), blk, 0, stream, X, R1a, R1b, NN);
        hipLaunchKernelGGL((transpose_convert<true>), gT, blk, 0, stream, W0, w0thi, w0tlo, N, D);
        // XW0 = X @ W0 -> xw0f
        hipLaunchKernelGGL((gemm_mfma<2, 3, 0>), gSlim, blk, 0, stream,
                           R1a, R1b, w0thi, w0tlo, (const float*)nullptr, xw0f,
                           (unsigned short*)nullptr, (unsigned short*)nullptr, N, D, N);
        hipLaunchKernelGGL((transpose_convert<true>), gT, blk, 0, stream, xw0f, xw0thi, xw0tlo, N, D);
        // A2 = U * softmax(L) -> hi/lo (overwrites X hi/lo)
        hipLaunchKernelGGL(softmax_mul_hilo, dim3(N), blk, 0, stream, Xp, U, R1a, R1b, N);
        // T = A2 @ XW0 -> Zp
        hipLaunchKernelGGL((gemm_mfma<2, 3, 0>), gSlim, blk, 0, stream,
                           R1a, R1b, xw0thi, xw0tlo, (const float*)nullptr, Zp,
                           (unsigned short*)nullptr, (unsigned short*)nullptr, N, D, N);
        // Z = softmax_rows(T) in place (final output 2)
        hipLaunchKernelGGL(softmax_inplace_small, dim3(N), blk, 0, stream, Zp, D);
        hipLaunchKernelGGL((transpose_convert<false>), gT, blk, 0, stream, Zp, zthi,
                           (unsigned short*)nullptr, N, D);
        // U -> hi only (overwrites A2)
        hipLaunchKernelGGL((convert_hilo<false>), dim3(cgrid), blk, 0, stream, U, R1a,
                           (unsigned short*)nullptr, NN);
        // UZ = U @ Z -> uzhi (bf16, sigmoid-tail precision is safe)
        hipLaunchKernelGGL((gemm_mfma<2, 1, 3>), gSlim, blk, 0, stream,
                           R1a, (const unsigned short*)nullptr, zthi, (const unsigned short*)nullptr,
                           (const float*)nullptr, (float*)nullptr, uzhi, (unsigned short*)nullptr, N, D, N);
        hipLaunchKernelGGL((transpose_convert<false>), gTw1, blk, 0, stream, W1, w1thi,
                           (unsigned short*)nullptr, D, N);
        // Xp = sigmoid(UZ @ W1)
        hipLaunchKernelGGL((gemm_mfma<4, 1, 2>), gBig, blk, 0, stream,
                           uzhi, (const unsigned short*)nullptr, w1thi, (const unsigned short*)nullptr,
                           (const float*)nullptr, Xp, (unsigned short*)nullptr, (unsigned short*)nullptr,
                           N, N, D);
    } else {
        // -------- fp32 fallback (round-1 path)
        float* bufA = (float*)d_ws;   // [N,D]
        dim3 gD(D / 128, N / 128);
        dim3 gN(N / 128, N / 128);
        hipLaunchKernelGGL((gemm_f32<1, true>),  gD, blk, 0, stream, U,    Wa, ba,      bufA, N, D, N);
        hipLaunchKernelGGL((gemm_f32<0, true>),  gN, blk, 0, stream, bufA, H1, nullptr, Xp,   N, N, D);
        hipLaunchKernelGGL(softmax_mul_f32, dim3(N), blk, 0, stream, Xp, U, N);
        hipLaunchKernelGGL((gemm_f32<0, false>), gD, blk, 0, stream, X,    W0, nullptr, bufA, N, D, N);
        hipLaunchKernelGGL((gemm_f32<0, false>), gD, blk, 0, stream, Xp,   bufA, nullptr, Zp, N, D, N);
        hipLaunchKernelGGL(softmax_inplace_small, dim3(N), blk, 0, stream, Zp, D);
        hipLaunchKernelGGL((gemm_f32<0, false>), gD, blk, 0, stream, U,    Zp, nullptr, bufA, N, D, N);
        hipLaunchKernelGGL((gemm_f32<2, false>), gN, blk, 0, stream, bufA, W1, nullptr, Xp,  N, N, D);
    }
}

// Round 3
// 1867.204 us; speedup vs baseline: 3.0377x; 1.0036x over previous
//
#include <hip/hip_runtime.h>
#include <math.h>

// GCNNet: N=8192, D=512.
// K  = tanh(U @ Wa^T + ba)        [N,D]   split-3 bf16 MFMA
// L  = K @ H1^T                   [N,N]   split-3
// A2 = U * softmax_rows(L)        [N,N]   (fused rowsum(A2))
// XW0= X @ W0                     [N,D]   split-3
// T  = A2 @ (XW0-c) + rs*c        [N,D]   split-2 x centered-single + rank-1
// Z  = softmax_rows(T)
// UZ = U @ Z                      [N,D]   single bf16 (sigmoid-saturated tail)
// Xp = sigmoid(UZ @ W1)           [N,N]   single bf16
// All GEMMs use chunked XCD swizzle (T1).

typedef __attribute__((ext_vector_type(8))) short bf16x8;
typedef __attribute__((ext_vector_type(4))) float f32x4;
typedef __attribute__((ext_vector_type(4))) unsigned short us4;

__device__ __forceinline__ unsigned short f2bf(float x) {
    unsigned int u = __float_as_uint(x);
    unsigned int r = (u + 0x7FFFu + ((u >> 16) & 1u)) >> 16;
    return (unsigned short)r;
}
__device__ __forceinline__ float bf2f(unsigned short h) {
    return __uint_as_float((unsigned int)h << 16);
}

__device__ __forceinline__ void gload_lds16(const char* g, char* l) {
    __builtin_amdgcn_global_load_lds(
        (const __attribute__((address_space(1))) unsigned int*)g,
        (__attribute__((address_space(3))) unsigned int*)l, 16, 0, 0);
}

// ---------------------------------------------------------------- converts
template<bool LO>
__global__ __launch_bounds__(256)
void convert_hilo(const float* __restrict__ in, unsigned short* __restrict__ hi,
                  unsigned short* __restrict__ lo, size_t n)
{
    size_t i = ((size_t)blockIdx.x * blockDim.x + threadIdx.x) * 4;
    const size_t stride = (size_t)gridDim.x * blockDim.x * 4;
    for (; i < n; i += stride) {
        float4 v = *(const float4*)(in + i);
        us4 h;
        h.x = f2bf(v.x); h.y = f2bf(v.y); h.z = f2bf(v.z); h.w = f2bf(v.w);
        *(us4*)(hi + i) = h;
        if (LO) {
            us4 l;
            l.x = f2bf(v.x - bf2f(h.x));
            l.y = f2bf(v.y - bf2f(h.y));
            l.z = f2bf(v.z - bf2f(h.z));
            l.w = f2bf(v.w - bf2f(h.w));
            *(us4*)(lo + i) = l;
        }
    }
}

// fp32 [R][C] -> bf16 hi/lo [C][R]; optional per-source-column subtract (CSUB)
template<bool LO, bool CSUB>
__global__ __launch_bounds__(256)
void transpose_convert(const float* __restrict__ in, unsigned short* __restrict__ hi,
                       unsigned short* __restrict__ lo, const float* __restrict__ cvec,
                       int R, int C)
{
    __shared__ float tile[32][33];
    const int t = threadIdx.x, tx = t & 31, ty = t >> 5;
    const int c0 = blockIdx.x * 32, r0 = blockIdx.y * 32;
#pragma unroll
    for (int i = 0; i < 4; ++i)
        tile[ty + 8 * i][tx] = in[(size_t)(r0 + ty + 8 * i) * C + c0 + tx];
    __syncthreads();
#pragma unroll
    for (int i = 0; i < 4; ++i) {
        const int col = c0 + ty + 8 * i;
        float v = tile[tx][ty + 8 * i];
        if (CSUB) v -= cvec[col];
        size_t o = (size_t)col * R + r0 + tx;
        unsigned short h = f2bf(v);
        hi[o] = h;
        if (LO) lo[o] = f2bf(v - bf2f(h));
    }
}

// column sums of [Nrows x 512] fp32 (atomic partials)
__global__ __launch_bounds__(256)
void colsum512(const float* __restrict__ in, float* __restrict__ c, int Nrows)
{
    const int t = threadIdx.x;
    const int r0 = blockIdx.x * 16;
    float s0 = 0.f, s1 = 0.f;
    for (int r = 0; r < 16; ++r) {
        const float* row = in + (size_t)(r0 + r) * 512;
        s0 += row[t];
        s1 += row[t + 256];
    }
    atomicAdd(&c[t], s0);
    atomicAdd(&c[t + 256], s1);
}

__global__ void scale_vec(float* __restrict__ c, float s, int n)
{
    const int t = threadIdx.x;
    if (t < n) c[t] *= s;
}

// ---------------------------------------------------------------- MFMA GEMM
// A: bf16 row-major [M,Kdim] (hi[,lo]); B: bf16 [Ncol,Kdim] (hi[,lo]).
// NPROD: 3 = Ahi*Bhi+Ahi*Blo+Alo*Bhi ; 2 = Ahi*Bh+Alo*Bh ; 1 = Ahi*Bh.
// EPI: 0 f32 store; 1 tanh(x+bias[col])->hi/lo; 2 sigmoid->f32; 3 bf16 hi;
//      4 f32 store of x + rs[row]*bias[col]  (rank-1 de-centering).
template<int FM, int NPROD, int EPI>
__global__ __launch_bounds__(256)
void gemm_mfma(const unsigned short* __restrict__ Ahi, const unsigned short* __restrict__ Alo,
               const unsigned short* __restrict__ Bhi, const unsigned short* __restrict__ Blo,
               const float* __restrict__ bias, const float* __restrict__ rs,
               float* __restrict__ Cf,
               unsigned short* __restrict__ Chi, unsigned short* __restrict__ Clo,
               int M, int Ncol, int Kdim)
{
    constexpr int BM = FM * 32;
    constexpr int BN = 128;
    constexpr int ABYTES = BM * 64;   // BM rows x 32 bf16 x 2B
    constexpr int BBYTES = BN * 64;
    constexpr int LDSB = ABYTES * (NPROD >= 2 ? 2 : 1) + BBYTES * (NPROD == 3 ? 2 : 1);
    constexpr int CPW = LDSB / 1024 / 4;   // 1KB chunks per wave

    __shared__ __align__(1024) char lds[LDSB];

    const int t = threadIdx.x;
    const int w = t >> 6, lane = t & 63;

    // chunked XCD swizzle (bijective: all grids used have nwg % 8 == 0)
    const int gx = gridDim.x;
    const int nwg = gx * gridDim.y;
    const int lid = blockIdx.y * gx + blockIdx.x;
    const int tl = (lid & 7) * (nwg >> 3) + (lid >> 3);
    const int m0 = (tl / gx) * BM, n0 = (tl % gx) * BN;

    const int wr = w >> 1, wc = w & 1;
    const int l15 = lane & 15, kq = lane >> 4;

    // staging: linear LDS regions per NPROD:
    //   NPROD==3: [Ahi][Bhi][Alo][Blo]; NPROD==2: [Ahi][Bh][Alo]; NPROD==1: [Ahi][Bh]
    const char* gsrc[CPW];
    char* lbase[CPW];
#pragma unroll
    for (int c = 0; c < CPW; ++c) {
        const int boff = (w * CPW + c) * 1024;
        lbase[c] = &lds[boff];
        const int poff = boff + lane * 16;
        const unsigned short* mat;
        int moff, rbase;
        if (poff < ABYTES)                     { mat = Ahi; moff = poff;                       rbase = m0; }
        else if (poff < ABYTES + BBYTES)       { mat = Bhi; moff = poff - ABYTES;              rbase = n0; }
        else if (poff < 2 * ABYTES + BBYTES)   { mat = Alo; moff = poff - ABYTES - BBYTES;     rbase = m0; }
        else                                   { mat = Blo; moff = poff - 2 * ABYTES - BBYTES; rbase = n0; }
        gsrc[c] = (const char*)(mat + (size_t)(rbase + (moff >> 6)) * Kdim) + (moff & 63);
    }

    int aoff[FM], boff_[4];
#pragma unroll
    for (int m = 0; m < FM; ++m)
        aoff[m] = (wr * (FM * 16) + m * 16 + l15) * 64 + kq * 16;
#pragma unroll
    for (int n = 0; n < 4; ++n)
        boff_[n] = (wc * 64 + n * 16 + l15) * 64 + kq * 16;

    f32x4 acc[FM][4];
#pragma unroll
    for (int m = 0; m < FM; ++m)
#pragma unroll
        for (int n = 0; n < 4; ++n)
            acc[m][n] = (f32x4)(0.f);

    const int ksteps = Kdim >> 5;
    for (int ks = 0; ks < ksteps; ++ks) {
#pragma unroll
        for (int c = 0; c < CPW; ++c) {
            gload_lds16(gsrc[c], lbase[c]);
            gsrc[c] += 64;   // 32 bf16 in K
        }
        __syncthreads();

        bf16x8 ah[FM], al[FM];
#pragma unroll
        for (int m = 0; m < FM; ++m) {
            ah[m] = *(const bf16x8*)(lds + aoff[m]);
            if constexpr (NPROD >= 2)
                al[m] = *(const bf16x8*)(lds + ABYTES + BBYTES + aoff[m]);
        }
#pragma unroll
        for (int n = 0; n < 4; ++n) {
            bf16x8 bh = *(const bf16x8*)(lds + ABYTES + boff_[n]);
#pragma unroll
            for (int m = 0; m < FM; ++m)
                acc[m][n] = __builtin_amdgcn_mfma_f32_16x16x32_bf16(ah[m], bh, acc[m][n], 0, 0, 0);
            if constexpr (NPROD == 3) {
                bf16x8 bl = *(const bf16x8*)(lds + 2 * ABYTES + BBYTES + boff_[n]);
#pragma unroll
                for (int m = 0; m < FM; ++m) {
                    acc[m][n] = __builtin_amdgcn_mfma_f32_16x16x32_bf16(ah[m], bl, acc[m][n], 0, 0, 0);
                    acc[m][n] = __builtin_amdgcn_mfma_f32_16x16x32_bf16(al[m], bh, acc[m][n], 0, 0, 0);
                }
            } else if constexpr (NPROD == 2) {
#pragma unroll
                for (int m = 0; m < FM; ++m)
                    acc[m][n] = __builtin_amdgcn_mfma_f32_16x16x32_bf16(al[m], bh, acc[m][n], 0, 0, 0);
            }
        }
        __syncthreads();
    }

    // epilogue: C/D frag layout col=lane&15, row=(lane>>4)*4+r
#pragma unroll
    for (int m = 0; m < FM; ++m) {
        const int rowb = m0 + wr * (FM * 16) + m * 16 + kq * 4;
#pragma unroll
        for (int n = 0; n < 4; ++n) {
            const int col = n0 + wc * 64 + n * 16 + l15;
#pragma unroll
            for (int r = 0; r < 4; ++r) {
                float v = acc[m][n][r];
                const size_t idx = (size_t)(rowb + r) * Ncol + col;
                if constexpr (EPI == 0) {
                    Cf[idx] = v;
                } else if constexpr (EPI == 1) {
                    v = tanhf(v + bias[col]);
                    unsigned short h = f2bf(v);
                    Chi[idx] = h;
                    Clo[idx] = f2bf(v - bf2f(h));
                } else if constexpr (EPI == 2) {
                    Cf[idx] = 1.f / (1.f + __expf(-v));
                } else if constexpr (EPI == 3) {
                    Chi[idx] = f2bf(v);
                } else {
                    Cf[idx] = v + rs[rowb + r] * bias[col];
                }
            }
        }
    }
}

// ---------------------------------------------------------------- reductions
__device__ inline float blockReduceMax(float v, float* sred)
{
    for (int o = 32; o > 0; o >>= 1) v = fmaxf(v, __shfl_down(v, o));
    const int lane = threadIdx.x & 63, wid = threadIdx.x >> 6;
    if (lane == 0) sred[wid] = v;
    __syncthreads();
    if (threadIdx.x == 0) {
        float m = sred[0];
        for (int w = 1; w < 4; ++w) m = fmaxf(m, sred[w]);
        sred[0] = m;
    }
    __syncthreads();
    float r = sred[0];
    __syncthreads();
    return r;
}

__device__ inline float blockReduceSum(float v, float* sred)
{
    for (int o = 32; o > 0; o >>= 1) v += __shfl_down(v, o);
    const int lane = threadIdx.x & 63, wid = threadIdx.x >> 6;
    if (lane == 0) sred[wid] = v;
    __syncthreads();
    if (threadIdx.x == 0) {
        float m = sred[0];
        for (int w = 1; w < 4; ++w) m += sred[w];
        sred[0] = m;
    }
    __syncthreads();
    float r = sred[0];
    __syncthreads();
    return r;
}

// A2 = U * softmax_rows(L) -> bf16 hi/lo + rowsum(A2); one block per row (Ncols=8192)
__global__ __launch_bounds__(256)
void softmax_mul_hilo(const float* __restrict__ Lrow, const float* __restrict__ U,
                      unsigned short* __restrict__ hi, unsigned short* __restrict__ lo,
                      float* __restrict__ rowsum, int Ncols)
{
    __shared__ float srow[8192];
    __shared__ float sred[8];
    const int t = threadIdx.x;
    const size_t base = (size_t)blockIdx.x * Ncols;

    float lmax = -3.402823466e38f;
    for (int c = t * 4; c < Ncols; c += 1024) {
        float4 v = *(const float4*)(Lrow + base + c);
        *(float4*)&srow[c] = v;
        lmax = fmaxf(lmax, fmaxf(fmaxf(v.x, v.y), fmaxf(v.z, v.w)));
    }
    const float rmax = blockReduceMax(lmax, sred);

    float lsum = 0.f;
    for (int c = t * 4; c < Ncols; c += 1024) {
        float4 v = *(float4*)&srow[c];
        v.x = __expf(v.x - rmax);
        v.y = __expf(v.y - rmax);
        v.z = __expf(v.z - rmax);
        v.w = __expf(v.w - rmax);
        *(float4*)&srow[c] = v;
        lsum += v.x + v.y + v.z + v.w;
    }
    const float rsum = blockReduceSum(lsum, sred);
    const float inv = 1.f / rsum;

    float a2sum = 0.f;
    for (int c = t * 4; c < Ncols; c += 1024) {
        float4 e = *(float4*)&srow[c];
        float4 u = *(const float4*)(U + base + c);
        float a0 = u.x * e.x * inv, a1 = u.y * e.y * inv;
        float a2 = u.z * e.z * inv, a3 = u.w * e.w * inv;
        a2sum += a0 + a1 + a2 + a3;
        us4 h, l;
        h.x = f2bf(a0); l.x = f2bf(a0 - bf2f(h.x));
        h.y = f2bf(a1); l.y = f2bf(a1 - bf2f(h.y));
        h.z = f2bf(a2); l.z = f2bf(a2 - bf2f(h.z));
        h.w = f2bf(a3); l.w = f2bf(a3 - bf2f(h.w));
        *(us4*)(hi + base + c) = h;
        *(us4*)(lo + base + c) = l;
    }
    const float rssum = blockReduceSum(a2sum, sred);
    if (t == 0) rowsum[blockIdx.x] = rssum;
}

// in-place row softmax, D=512, one block per row
__global__ __launch_bounds__(256)
void softmax_inplace_small(float* buf, int D)
{
    __shared__ float sred[8];
    const int t = threadIdx.x;
    const size_t base = (size_t)blockIdx.x * D;
    float2 v = *(float2*)(buf + base + t * 2);
    const float rmax = blockReduceMax(fmaxf(v.x, v.y), sred);
    const float e0 = __expf(v.x - rmax);
    const float e1 = __expf(v.y - rmax);
    const float rsum = blockReduceSum(e0 + e1, sred);
    const float inv = 1.f / rsum;
    float2 o;
    o.x = e0 * inv;
    o.y = e1 * inv;
    *(float2*)(buf + base + t * 2) = o;
}

// ---------------------------------------------------------------- fp32 fallback
template<int EPI, bool TB>
__global__ __launch_bounds__(256)
void gemm_f32(const float* __restrict__ A, const float* __restrict__ B,
              const float* __restrict__ bias, float* __restrict__ C,
              int M, int Ncol, int Kdim)
{
    constexpr int FBM = 128, FBN = 128, FBK = 8;
    __shared__ float As[FBK][FBM];
    __shared__ float Bs[FBK][FBN];
    const int t  = threadIdx.x;
    const int tx = t & 15, ty = t >> 4;
    const int m0 = blockIdx.y * FBM, n0 = blockIdx.x * FBN;

    const int arow  = t >> 1;
    const int acol4 = (t & 1) * 4;
    const int brow  = t >> 5;
    const int bcol4 = (t & 31) * 4;

    float acc[8][8];
#pragma unroll
    for (int i = 0; i < 8; ++i)
#pragma unroll
        for (int j = 0; j < 8; ++j) acc[i][j] = 0.f;

    const float* Aptr = A + (size_t)(m0 + arow) * Kdim + acol4;
    const float* Bptr;
    if (TB) Bptr = B + (size_t)(n0 + arow) * Kdim + acol4;
    else    Bptr = B + (size_t)brow * Ncol + n0 + bcol4;

    float4 av = *(const float4*)(Aptr);
    float4 bv = *(const float4*)(Bptr);

    for (int k0 = 0; k0 < Kdim; k0 += FBK) {
        As[acol4 + 0][arow] = av.x;
        As[acol4 + 1][arow] = av.y;
        As[acol4 + 2][arow] = av.z;
        As[acol4 + 3][arow] = av.w;
        if (TB) {
            Bs[acol4 + 0][arow] = bv.x;
            Bs[acol4 + 1][arow] = bv.y;
            Bs[acol4 + 2][arow] = bv.z;
            Bs[acol4 + 3][arow] = bv.w;
        } else {
            *(float4*)&Bs[brow][bcol4] = bv;
        }
        __syncthreads();

        if (k0 + FBK < Kdim) {
            av = *(const float4*)(Aptr + (k0 + FBK));
            if (TB) bv = *(const float4*)(Bptr + (k0 + FBK));
            else    bv = *(const float4*)(Bptr + (size_t)(k0 + FBK) * Ncol);
        }

#pragma unroll
        for (int kk = 0; kk < FBK; ++kk) {
            float a[8], b[8];
            *(float4*)&a[0] = *(const float4*)&As[kk][ty * 4];
            *(float4*)&a[4] = *(const float4*)&As[kk][64 + ty * 4];
            *(float4*)&b[0] = *(const float4*)&Bs[kk][tx * 4];
            *(float4*)&b[4] = *(const float4*)&Bs[kk][64 + tx * 4];
#pragma unroll
            for (int i = 0; i < 8; ++i)
#pragma unroll
                for (int j = 0; j < 8; ++j)
                    acc[i][j] = fmaf(a[i], b[j], acc[i][j]);
        }
        __syncthreads();
    }

#pragma unroll
    for (int ib = 0; ib < 2; ++ib) {
#pragma unroll
        for (int ii = 0; ii < 4; ++ii) {
            const int i = ib * 4 + ii;
            const size_t row = (size_t)(m0 + ib * 64 + ty * 4 + ii);
            float* crow = C + row * (size_t)Ncol;
#pragma unroll
            for (int jb = 0; jb < 2; ++jb) {
                const int col0 = n0 + jb * 64 + tx * 4;
                float4 v;
                v.x = acc[i][jb * 4 + 0];
                v.y = acc[i][jb * 4 + 1];
                v.z = acc[i][jb * 4 + 2];
                v.w = acc[i][jb * 4 + 3];
                if (EPI == 1) {
                    v.x = tanhf(v.x + bias[col0 + 0]);
                    v.y = tanhf(v.y + bias[col0 + 1]);
                    v.z = tanhf(v.z + bias[col0 + 2]);
                    v.w = tanhf(v.w + bias[col0 + 3]);
                } else if (EPI == 2) {
                    v.x = 1.f / (1.f + __expf(-v.x));
                    v.y = 1.f / (1.f + __expf(-v.y));
                    v.z = 1.f / (1.f + __expf(-v.z));
                    v.w = 1.f / (1.f + __expf(-v.w));
                }
                *(float4*)(crow + col0) = v;
            }
        }
    }
}

__global__ __launch_bounds__(256)
void softmax_mul_f32(float* buf, const float* __restrict__ U, int Ncols)
{
    __shared__ float srow[8192];
    __shared__ float sred[8];
    const int t = threadIdx.x;
    const size_t base = (size_t)blockIdx.x * Ncols;

    float lmax = -3.402823466e38f;
    for (int c = t * 4; c < Ncols; c += 1024) {
        float4 v = *(const float4*)(buf + base + c);
        *(float4*)&srow[c] = v;
        lmax = fmaxf(lmax, fmaxf(fmaxf(v.x, v.y), fmaxf(v.z, v.w)));
    }
    const float rmax = blockReduceMax(lmax, sred);

    float lsum = 0.f;
    for (int c = t * 4; c < Ncols; c += 1024) {
        float4 v = *(float4*)&srow[c];
        v.x = __expf(v.x - rmax);
        v.y = __expf(v.y - rmax);
        v.z = __expf(v.z - rmax);
        v.w = __expf(v.w - rmax);
        *(float4*)&srow[c] = v;
        lsum += v.x + v.y + v.z + v.w;
    }
    const float rsum = blockReduceSum(lsum, sred);
    const float inv = 1.f / rsum;

    for (int c = t * 4; c < Ncols; c += 1024) {
        float4 e = *(float4*)&srow[c];
        float4 u = *(const float4*)(U + base + c);
        float4 o;
        o.x = u.x * e.x * inv;
        o.y = u.y * e.y * inv;
        o.z = u.z * e.z * inv;
        o.w = u.w * e.w * inv;
        *(float4*)(buf + base + c) = o;
    }
}

// ---------------------------------------------------------------- launch
extern "C" void kernel_launch(void* const* d_in, const int* in_sizes, int n_in,
                              void* d_out, int out_size, void* d_ws, size_t ws_size,
                              hipStream_t stream)
{
    const float* U  = (const float*)d_in[0];
    const float* X  = (const float*)d_in[1];
    const float* H1 = (const float*)d_in[2];
    const float* W0 = (const float*)d_in[3];
    const float* W1 = (const float*)d_in[4];
    const float* Wa = (const float*)d_in[5];
    const float* ba = (const float*)d_in[6];
    const int D = in_sizes[6];
    const int N = (int)((long long)in_sizes[2] / D);
    const size_t NN = (size_t)N * N, ND = (size_t)N * D;

    float* Xp = (float*)d_out;          // [N,N] final; also scratch for L
    float* Zp = Xp + NN;                // [N,D] final Z; also scratch for T

    // ---- workspace layout for MFMA path
    char* p = (char*)d_ws;
    auto alloc = [&](size_t bytes) { char* r = p; p += (bytes + 255) & ~(size_t)255; return r; };
    unsigned short* R1a   = (unsigned short*)alloc(NN * 2);   // Uhi / Xhi / A2hi / Uhi2
    unsigned short* R1b   = (unsigned short*)alloc(NN * 2);   // Ulo / Xlo / A2lo
    unsigned short* wahi  = (unsigned short*)alloc(ND * 2);
    unsigned short* walo  = (unsigned short*)alloc(ND * 2);
    unsigned short* h1hi  = (unsigned short*)alloc(ND * 2);
    unsigned short* h1lo  = (unsigned short*)alloc(ND * 2);
    unsigned short* khi   = (unsigned short*)alloc(ND * 2);
    unsigned short* klo   = (unsigned short*)alloc(ND * 2);
    unsigned short* w0thi = (unsigned short*)alloc(ND * 2);
    unsigned short* w0tlo = (unsigned short*)alloc(ND * 2);
    unsigned short* vbt   = (unsigned short*)alloc(ND * 2);   // centered XW0^T bf16
    unsigned short* zthi  = (unsigned short*)alloc(ND * 2);
    unsigned short* uzhi  = (unsigned short*)alloc(ND * 2);
    unsigned short* w1thi = (unsigned short*)alloc(ND * 2);
    float*          xw0f  = (float*)alloc(ND * 4);
    float*          cvec  = (float*)alloc((size_t)D * 4);
    float*          rsum  = (float*)alloc((size_t)N * 4);
    const size_t need = (size_t)(p - (char*)d_ws);

    dim3 blk(256);

    if (N == 8192 && D == 512 && ws_size >= need) {
        // -------- MFMA split-bf16 path
        const dim3 gSlim(D / 128, N / 64);    // (4,128) slim GEMMs
        const dim3 gBig(N / 128, N / 128);    // (64,64) big GEMMs
        const dim3 gT(D / 32, N / 32);        // [N,D] -> [D,N]
        const dim3 gTw1(N / 32, D / 32);      // [D,N] -> [N,D]
        const int cgrid = 4096;
        const unsigned short* nullu = nullptr;
        const float* nullf = nullptr;

        // U -> hi/lo
        hipLaunchKernelGGL((convert_hilo<true>), dim3(cgrid), blk, 0, stream, U, R1a, R1b, NN);
        hipLaunchKernelGGL((convert_hilo<true>), dim3(512),  blk, 0, stream, Wa, wahi, walo, ND);
        // K = tanh(U @ Wa^T + ba) -> khi/klo   [split-3]
        hipLaunchKernelGGL((gemm_mfma<2, 3, 1>), gSlim, blk, 0, stream,
                           R1a, R1b, wahi, walo, ba, nullf, (float*)nullptr, khi, klo, N, D, N);
        hipLaunchKernelGGL((convert_hilo<true>), dim3(512), blk, 0, stream, H1, h1hi, h1lo, ND);
        // L = K @ H1^T -> Xp   [split-3]
        hipLaunchKernelGGL((gemm_mfma<4, 3, 0>), gBig, blk, 0, stream,
                           khi, klo, h1hi, h1lo, nullf, nullf, Xp,
                           (unsigned short*)nullptr, (unsigned short*)nullptr, N, N, D);
        // X -> hi/lo (overwrites U hi/lo)
        hipLaunchKernelGGL((convert_hilo<true>), dim3(cgrid), blk, 0, stream, X, R1a, R1b, NN);
        hipLaunchKernelGGL((transpose_convert<true, false>), gT, blk, 0, stream,
                           W0, w0thi, w0tlo, nullf, N, D);
        // XW0 = X @ W0 -> xw0f   [split-3]
        hipLaunchKernelGGL((gemm_mfma<2, 3, 0>), gSlim, blk, 0, stream,
                           R1a, R1b, w0thi, w0tlo, nullf, nullf, xw0f,
                           (unsigned short*)nullptr, (unsigned short*)nullptr, N, D, N);
        // column means of XW0
        hipMemsetAsync(cvec, 0, (size_t)D * 4, stream);
        hipLaunchKernelGGL(colsum512, dim3(N / 16), blk, 0, stream, xw0f, cvec, N);
        hipLaunchKernelGGL(scale_vec, dim3(1), dim3(512), 0, stream, cvec, 1.0f / (float)N, D);
        // V = (XW0 - c)^T -> bf16 [D][N]
        hipLaunchKernelGGL((transpose_convert<false, true>), gT, blk, 0, stream,
                           xw0f, vbt, (unsigned short*)nullptr, cvec, N, D);
        // A2 = U * softmax(L) -> hi/lo + rowsum (overwrites X hi/lo)
        hipLaunchKernelGGL(softmax_mul_hilo, dim3(N), blk, 0, stream, Xp, U, R1a, R1b, rsum, N);
        // T = A2 @ V + rsum (x) c -> Zp   [split-2 + rank-1]
        hipLaunchKernelGGL((gemm_mfma<2, 2, 4>), gSlim, blk, 0, stream,
                           R1a, R1b, vbt, nullu, cvec, rsum, Zp,
                           (unsigned short*)nullptr, (unsigned short*)nullptr, N, D, N);
        // Z = softmax_rows(T) in place
        hipLaunchKernelGGL(softmax_inplace_small, dim3(N), blk, 0, stream, Zp, D);
        hipLaunchKernelGGL((transpose_convert<false, false>), gT, blk, 0, stream,
                           Zp, zthi, (unsigned short*)nullptr, nullf, N, D);
        // U -> hi only (overwrites A2)
        hipLaunchKernelGGL((convert_hilo<false>), dim3(cgrid), blk, 0, stream, U, R1a,
                           (unsigned short*)nullptr, NN);
        // UZ = U @ Z -> uzhi   [single]
        hipLaunchKernelGGL((gemm_mfma<2, 1, 3>), gSlim, blk, 0, stream,
                           R1a, nullu, zthi, nullu, nullf, nullf, (float*)nullptr,
                           uzhi, (unsigned short*)nullptr, N, D, N);
        hipLaunchKernelGGL((transpose_convert<false, false>), gTw1, blk, 0, stream,
                           W1, w1thi, (unsigned short*)nullptr, nullf, D, N);
        // Xp = sigmoid(UZ @ W1)   [single]
        hipLaunchKernelGGL((gemm_mfma<4, 1, 2>), gBig, blk, 0, stream,
                           uzhi, nullu, w1thi, nullu, nullf, nullf, Xp,
                           (unsigned short*)nullptr, (unsigned short*)nullptr, N, N, D);
    } else {
        // -------- fp32 fallback
        float* bufA = (float*)d_ws;   // [N,D]
        dim3 gD(D / 128, N / 128);
        dim3 gN(N / 128, N / 128);
        hipLaunchKernelGGL((gemm_f32<1, true>),  gD, blk, 0, stream, U,    Wa, ba,      bufA, N, D, N);
        hipLaunchKernelGGL((gemm_f32<0, true>),  gN, blk, 0, stream, bufA, H1, nullptr, Xp,   N, N, D);
        hipLaunchKernelGGL(softmax_mul_f32, dim3(N), blk, 0, stream, Xp, U, N);
        hipLaunchKernelGGL((gemm_f32<0, false>), gD, blk, 0, stream, X,    W0, nullptr, bufA, N, D, N);
        hipLaunchKernelGGL((gemm_f32<0, false>), gD, blk, 0, stream, Xp,   bufA, nullptr, Zp, N, D, N);
        hipLaunchKernelGGL(softmax_inplace_small, dim3(N), blk, 0, stream, Zp, D);
        hipLaunchKernelGGL((gemm_f32<0, false>), gD, blk, 0, stream, U,    Zp, nullptr, bufA, N, D, N);
        hipLaunchKernelGGL((gemm_f32<2, false>), gN, blk, 0, stream, bufA, W1, nullptr, Xp,  N, N, D);
    }
}

// Round 4
// 1496.266 us; speedup vs baseline: 3.7907x; 1.2479x over previous
//
#include <hip/hip_runtime.h>
#include <math.h>

// GCNNet: N=8192, D=512.
//   K  = tanh(U @ Wa^T + ba)   [N,D]  fp16 A-split2 x B-single MFMA
//   L  = K @ H1^T              [N,N]  fp16 A-split2 x B-single
//   A2 = U * softmax_rows(L)   [N,N]  (fused rowsum)
//   XW0= X @ W0                [N,D]  fp16 A-split2 x B-single
//   T  = A2 @ (XW0-c) + rs*c   [N,D]  bf16 A-split2 x B-single + rank-1
//   Z  = softmax_rows(T)
//   UZ = U @ Z                 [N,D]  fp16 single
//   Xp = sigmoid(UZ @ W1)      [N,N]  fp16 single
// GEMMs: 2-phase double-buffered LDS pipeline (one barrier per k-step),
// chunked XCD swizzle, setprio around MFMA cluster.

typedef __attribute__((ext_vector_type(8))) short bf16x8;
typedef __attribute__((ext_vector_type(8))) _Float16 f16x8;
typedef __attribute__((ext_vector_type(4))) float f32x4;
typedef __attribute__((ext_vector_type(4))) unsigned short us4;

__device__ __forceinline__ unsigned short f2bf(float x) {
    unsigned int u = __float_as_uint(x);
    unsigned int r = (u + 0x7FFFu + ((u >> 16) & 1u)) >> 16;
    return (unsigned short)r;
}
__device__ __forceinline__ float bf2f(unsigned short h) {
    return __uint_as_float((unsigned int)h << 16);
}
__device__ __forceinline__ unsigned short f2h(float x) {
    _Float16 h = (_Float16)x;
    return __builtin_bit_cast(unsigned short, h);
}
__device__ __forceinline__ float h2f(unsigned short u) {
    return (float)__builtin_bit_cast(_Float16, u);
}

__device__ __forceinline__ void gload_lds16(const char* g, char* l) {
    __builtin_amdgcn_global_load_lds(
        (const __attribute__((address_space(1))) unsigned int*)g,
        (__attribute__((address_space(3))) unsigned int*)l, 16, 0, 0);
}

__device__ __forceinline__ f32x4 mfma_any(bf16x8 a, bf16x8 b, f32x4 c, bool fp16) {
    if (fp16)
        return __builtin_amdgcn_mfma_f32_16x16x32_f16(
            __builtin_bit_cast(f16x8, a), __builtin_bit_cast(f16x8, b), c, 0, 0, 0);
    return __builtin_amdgcn_mfma_f32_16x16x32_bf16(a, b, c, 0, 0, 0);
}

// ---------------------------------------------------------------- converts
// fp32 -> hi[,lo] in FP16 or BF16
template<bool LO, bool FP16>
__global__ __launch_bounds__(256)
void convert_split(const float* __restrict__ in, unsigned short* __restrict__ hi,
                   unsigned short* __restrict__ lo, size_t n)
{
    size_t i = ((size_t)blockIdx.x * blockDim.x + threadIdx.x) * 4;
    const size_t stride = (size_t)gridDim.x * blockDim.x * 4;
    for (; i < n; i += stride) {
        float4 v = *(const float4*)(in + i);
        us4 h;
        if (FP16) { h.x = f2h(v.x); h.y = f2h(v.y); h.z = f2h(v.z); h.w = f2h(v.w); }
        else      { h.x = f2bf(v.x); h.y = f2bf(v.y); h.z = f2bf(v.z); h.w = f2bf(v.w); }
        *(us4*)(hi + i) = h;
        if (LO) {
            us4 l;
            if (FP16) {
                l.x = f2h(v.x - h2f(h.x)); l.y = f2h(v.y - h2f(h.y));
                l.z = f2h(v.z - h2f(h.z)); l.w = f2h(v.w - h2f(h.w));
            } else {
                l.x = f2bf(v.x - bf2f(h.x)); l.y = f2bf(v.y - bf2f(h.y));
                l.z = f2bf(v.z - bf2f(h.z)); l.w = f2bf(v.w - bf2f(h.w));
            }
            *(us4*)(lo + i) = l;
        }
    }
}

// fp32 [R][C] -> hi [C][R]; optional per-source-column subtract
template<bool CSUB, bool FP16>
__global__ __launch_bounds__(256)
void transpose_cvt(const float* __restrict__ in, unsigned short* __restrict__ hi,
                   const float* __restrict__ cvec, int R, int C)
{
    __shared__ float tile[32][33];
    const int t = threadIdx.x, tx = t & 31, ty = t >> 5;
    const int c0 = blockIdx.x * 32, r0 = blockIdx.y * 32;
#pragma unroll
    for (int i = 0; i < 4; ++i)
        tile[ty + 8 * i][tx] = in[(size_t)(r0 + ty + 8 * i) * C + c0 + tx];
    __syncthreads();
#pragma unroll
    for (int i = 0; i < 4; ++i) {
        const int col = c0 + ty + 8 * i;
        float v = tile[tx][ty + 8 * i];
        if (CSUB) v -= cvec[col];
        size_t o = (size_t)col * R + r0 + tx;
        hi[o] = FP16 ? f2h(v) : f2bf(v);
    }
}

// column sums of [Nrows x 512] fp32 (atomic partials)
__global__ __launch_bounds__(256)
void colsum512(const float* __restrict__ in, float* __restrict__ c, int Nrows)
{
    const int t = threadIdx.x;
    const int r0 = blockIdx.x * 16;
    float s0 = 0.f, s1 = 0.f;
    for (int r = 0; r < 16; ++r) {
        const float* row = in + (size_t)(r0 + r) * 512;
        s0 += row[t];
        s1 += row[t + 256];
    }
    atomicAdd(&c[t], s0);
    atomicAdd(&c[t + 256], s1);
}

__global__ void scale_vec(float* __restrict__ c, float s, int n)
{
    const int t = threadIdx.x;
    if (t < n) c[t] *= s;
}

// ---------------------------------------------------------------- MFMA GEMM
// A: hi[,lo] row-major [M,Kdim]; B: hi [Ncol,Kdim]. 2B elements (fp16 or bf16).
// NPROD: 2 = Ah*Bh + Al*Bh ; 1 = Ah*Bh.
// EPI: 0 f32; 1 tanh(x+bias[col])->hi/lo; 2 sigmoid->f32; 3 hi-only;
//      4 f32 of x + rs[row]*bias[col].
template<int FM, int NPROD, int EPI, bool FP16>
__global__ __launch_bounds__(256)
void gemm_mfma(const unsigned short* __restrict__ Ahi, const unsigned short* __restrict__ Alo,
               const unsigned short* __restrict__ Bh,
               const float* __restrict__ bias, const float* __restrict__ rs,
               float* __restrict__ Cf, unsigned short* __restrict__ Chi,
               unsigned short* __restrict__ Clo,
               int M, int Ncol, int Kdim)
{
    constexpr int BM = FM * 32;
    constexpr int BN = 128;
    constexpr int ABYTES = BM * 64;           // BM rows x 32 elems x 2B
    constexpr int BBYTES = BN * 64;
    constexpr int LDSB = ABYTES * NPROD + BBYTES;   // [Ah][Bh][Al?]
    constexpr int CPW = LDSB / 1024 / 4;      // 1KB chunks per wave

    __shared__ __align__(1024) char lds[2][LDSB];

    const int t = threadIdx.x;
    const int w = t >> 6, lane = t & 63;

    // chunked XCD swizzle (bijective: grids are multiples of 8)
    const int gx = gridDim.x;
    const int nwg = gx * gridDim.y;
    const int lid = blockIdx.y * gx + blockIdx.x;
    const int tl = (lid & 7) * (nwg >> 3) + (lid >> 3);
    const int m0 = (tl / gx) * BM, n0 = (tl % gx) * BN;

    const int wr = w >> 1, wc = w & 1;
    const int l15 = lane & 15, kq = lane >> 4;

    const char* gsrc[CPW];
    int lofs[CPW];
#pragma unroll
    for (int c = 0; c < CPW; ++c) {
        const int boff = (w * CPW + c) * 1024;
        lofs[c] = boff;
        const int poff = boff + lane * 16;
        const unsigned short* mat;
        int moff, rbase;
        if (poff < ABYTES)               { mat = Ahi; moff = poff;                   rbase = m0; }
        else if (poff < ABYTES + BBYTES) { mat = Bh;  moff = poff - ABYTES;          rbase = n0; }
        else                             { mat = Alo; moff = poff - ABYTES - BBYTES; rbase = m0; }
        gsrc[c] = (const char*)(mat + (size_t)(rbase + (moff >> 6)) * Kdim) + (moff & 63);
    }

    int aoff[FM], boff_[4];
#pragma unroll
    for (int m = 0; m < FM; ++m)
        aoff[m] = (wr * (FM * 16) + m * 16 + l15) * 64 + kq * 16;
#pragma unroll
    for (int n = 0; n < 4; ++n)
        boff_[n] = (wc * 64 + n * 16 + l15) * 64 + kq * 16;

    f32x4 acc[FM][4];
#pragma unroll
    for (int m = 0; m < FM; ++m)
#pragma unroll
        for (int n = 0; n < 4; ++n)
            acc[m][n] = (f32x4)(0.f);

    auto stage = [&](int buf) {
#pragma unroll
        for (int c = 0; c < CPW; ++c) {
            gload_lds16(gsrc[c], &lds[buf][lofs[c]]);
            gsrc[c] += 64;   // advance 32 elems in K
        }
    };

    const int ksteps = Kdim >> 5;
    stage(0);
    __syncthreads();

    int cur = 0;
    for (int ks = 0; ks < ksteps; ++ks) {
        if (ks + 1 < ksteps) stage(cur ^ 1);   // prefetch next k-tile (overlaps MFMA)

        const char* Lb = lds[cur];
        bf16x8 ah[FM], al[FM], bb[4];
#pragma unroll
        for (int m = 0; m < FM; ++m) {
            ah[m] = *(const bf16x8*)(Lb + aoff[m]);
            if constexpr (NPROD == 2)
                al[m] = *(const bf16x8*)(Lb + ABYTES + BBYTES + aoff[m]);
        }
#pragma unroll
        for (int n = 0; n < 4; ++n)
            bb[n] = *(const bf16x8*)(Lb + ABYTES + boff_[n]);

        __builtin_amdgcn_s_setprio(1);
#pragma unroll
        for (int n = 0; n < 4; ++n) {
#pragma unroll
            for (int m = 0; m < FM; ++m) {
                acc[m][n] = mfma_any(ah[m], bb[n], acc[m][n], FP16);
                if constexpr (NPROD == 2)
                    acc[m][n] = mfma_any(al[m], bb[n], acc[m][n], FP16);
            }
        }
        __builtin_amdgcn_s_setprio(0);

        __syncthreads();   // drains staged loads (vmcnt) + lgkm once per k-step
        cur ^= 1;
    }

    // epilogue: C/D frag layout col=lane&15, row=(lane>>4)*4+r
#pragma unroll
    for (int m = 0; m < FM; ++m) {
        const int rowb = m0 + wr * (FM * 16) + m * 16 + kq * 4;
#pragma unroll
        for (int n = 0; n < 4; ++n) {
            const int col = n0 + wc * 64 + n * 16 + l15;
#pragma unroll
            for (int r = 0; r < 4; ++r) {
                float v = acc[m][n][r];
                const size_t idx = (size_t)(rowb + r) * Ncol + col;
                if constexpr (EPI == 0) {
                    Cf[idx] = v;
                } else if constexpr (EPI == 1) {
                    v = tanhf(v + bias[col]);
                    if (FP16) { unsigned short h = f2h(v);  Chi[idx] = h; Clo[idx] = f2h(v - h2f(h)); }
                    else      { unsigned short h = f2bf(v); Chi[idx] = h; Clo[idx] = f2bf(v - bf2f(h)); }
                } else if constexpr (EPI == 2) {
                    Cf[idx] = 1.f / (1.f + __expf(-v));
                } else if constexpr (EPI == 3) {
                    Chi[idx] = FP16 ? f2h(v) : f2bf(v);
                } else {
                    Cf[idx] = v + rs[rowb + r] * bias[col];
                }
            }
        }
    }
}

// ---------------------------------------------------------------- reductions
__device__ inline float blockReduceMax(float v, float* sred)
{
    for (int o = 32; o > 0; o >>= 1) v = fmaxf(v, __shfl_down(v, o));
    const int lane = threadIdx.x & 63, wid = threadIdx.x >> 6;
    if (lane == 0) sred[wid] = v;
    __syncthreads();
    if (threadIdx.x == 0) {
        float m = sred[0];
        for (int w = 1; w < 4; ++w) m = fmaxf(m, sred[w]);
        sred[0] = m;
    }
    __syncthreads();
    float r = sred[0];
    __syncthreads();
    return r;
}

__device__ inline float blockReduceSum(float v, float* sred)
{
    for (int o = 32; o > 0; o >>= 1) v += __shfl_down(v, o);
    const int lane = threadIdx.x & 63, wid = threadIdx.x >> 6;
    if (lane == 0) sred[wid] = v;
    __syncthreads();
    if (threadIdx.x == 0) {
        float m = sred[0];
        for (int w = 1; w < 4; ++w) m += sred[w];
        sred[0] = m;
    }
    __syncthreads();
    float r = sred[0];
    __syncthreads();
    return r;
}

// A2 = U * softmax_rows(L) -> bf16 hi/lo + rowsum(A2); one block per row
__global__ __launch_bounds__(256)
void softmax_mul_hilo(const float* __restrict__ Lrow, const float* __restrict__ U,
                      unsigned short* __restrict__ hi, unsigned short* __restrict__ lo,
                      float* __restrict__ rowsum, int Ncols)
{
    __shared__ float srow[8192];
    __shared__ float sred[8];
    const int t = threadIdx.x;
    const size_t base = (size_t)blockIdx.x * Ncols;

    float lmax = -3.402823466e38f;
    for (int c = t * 4; c < Ncols; c += 1024) {
        float4 v = *(const float4*)(Lrow + base + c);
        *(float4*)&srow[c] = v;
        lmax = fmaxf(lmax, fmaxf(fmaxf(v.x, v.y), fmaxf(v.z, v.w)));
    }
    const float rmax = blockReduceMax(lmax, sred);

    float lsum = 0.f;
    for (int c = t * 4; c < Ncols; c += 1024) {
        float4 v = *(float4*)&srow[c];
        v.x = __expf(v.x - rmax);
        v.y = __expf(v.y - rmax);
        v.z = __expf(v.z - rmax);
        v.w = __expf(v.w - rmax);
        *(float4*)&srow[c] = v;
        lsum += v.x + v.y + v.z + v.w;
    }
    const float rsum = blockReduceSum(lsum, sred);
    const float inv = 1.f / rsum;

    float a2sum = 0.f;
    for (int c = t * 4; c < Ncols; c += 1024) {
        float4 e = *(float4*)&srow[c];
        float4 u = *(const float4*)(U + base + c);
        float a0 = u.x * e.x * inv, a1 = u.y * e.y * inv;
        float a2 = u.z * e.z * inv, a3 = u.w * e.w * inv;
        a2sum += a0 + a1 + a2 + a3;
        us4 h, l;
        h.x = f2bf(a0); l.x = f2bf(a0 - bf2f(h.x));
        h.y = f2bf(a1); l.y = f2bf(a1 - bf2f(h.y));
        h.z = f2bf(a2); l.z = f2bf(a2 - bf2f(h.z));
        h.w = f2bf(a3); l.w = f2bf(a3 - bf2f(h.w));
        *(us4*)(hi + base + c) = h;
        *(us4*)(lo + base + c) = l;
    }
    const float rssum = blockReduceSum(a2sum, sred);
    if (t == 0) rowsum[blockIdx.x] = rssum;
}

// in-place row softmax, D=512, one block per row
__global__ __launch_bounds__(256)
void softmax_inplace_small(float* buf, int D)
{
    __shared__ float sred[8];
    const int t = threadIdx.x;
    const size_t base = (size_t)blockIdx.x * D;
    float2 v = *(float2*)(buf + base + t * 2);
    const float rmax = blockReduceMax(fmaxf(v.x, v.y), sred);
    const float e0 = __expf(v.x - rmax);
    const float e1 = __expf(v.y - rmax);
    const float rsum = blockReduceSum(e0 + e1, sred);
    const float inv = 1.f / rsum;
    float2 o;
    o.x = e0 * inv;
    o.y = e1 * inv;
    *(float2*)(buf + base + t * 2) = o;
}

// ---------------------------------------------------------------- fp32 fallback
template<int EPI, bool TB>
__global__ __launch_bounds__(256)
void gemm_f32(const float* __restrict__ A, const float* __restrict__ B,
              const float* __restrict__ bias, float* __restrict__ C,
              int M, int Ncol, int Kdim)
{
    constexpr int FBM = 128, FBN = 128, FBK = 8;
    __shared__ float As[FBK][FBM];
    __shared__ float Bs[FBK][FBN];
    const int t  = threadIdx.x;
    const int tx = t & 15, ty = t >> 4;
    const int m0 = blockIdx.y * FBM, n0 = blockIdx.x * FBN;

    const int arow  = t >> 1;
    const int acol4 = (t & 1) * 4;
    const int brow  = t >> 5;
    const int bcol4 = (t & 31) * 4;

    float acc[8][8];
#pragma unroll
    for (int i = 0; i < 8; ++i)
#pragma unroll
        for (int j = 0; j < 8; ++j) acc[i][j] = 0.f;

    const float* Aptr = A + (size_t)(m0 + arow) * Kdim + acol4;
    const float* Bptr;
    if (TB) Bptr = B + (size_t)(n0 + arow) * Kdim + acol4;
    else    Bptr = B + (size_t)brow * Ncol + n0 + bcol4;

    float4 av = *(const float4*)(Aptr);
    float4 bv = *(const float4*)(Bptr);

    for (int k0 = 0; k0 < Kdim; k0 += FBK) {
        As[acol4 + 0][arow] = av.x;
        As[acol4 + 1][arow] = av.y;
        As[acol4 + 2][arow] = av.z;
        As[acol4 + 3][arow] = av.w;
        if (TB) {
            Bs[acol4 + 0][arow] = bv.x;
            Bs[acol4 + 1][arow] = bv.y;
            Bs[acol4 + 2][arow] = bv.z;
            Bs[acol4 + 3][arow] = bv.w;
        } else {
            *(float4*)&Bs[brow][bcol4] = bv;
        }
        __syncthreads();

        if (k0 + FBK < Kdim) {
            av = *(const float4*)(Aptr + (k0 + FBK));
            if (TB) bv = *(const float4*)(Bptr + (k0 + FBK));
            else    bv = *(const float4*)(Bptr + (size_t)(k0 + FBK) * Ncol);
        }

#pragma unroll
        for (int kk = 0; kk < FBK; ++kk) {
            float a[8], b[8];
            *(float4*)&a[0] = *(const float4*)&As[kk][ty * 4];
            *(float4*)&a[4] = *(const float4*)&As[kk][64 + ty * 4];
            *(float4*)&b[0] = *(const float4*)&Bs[kk][tx * 4];
            *(float4*)&b[4] = *(const float4*)&Bs[kk][64 + tx * 4];
#pragma unroll
            for (int i = 0; i < 8; ++i)
#pragma unroll
                for (int j = 0; j < 8; ++j)
                    acc[i][j] = fmaf(a[i], b[j], acc[i][j]);
        }
        __syncthreads();
    }

#pragma unroll
    for (int ib = 0; ib < 2; ++ib) {
#pragma unroll
        for (int ii = 0; ii < 4; ++ii) {
            const int i = ib * 4 + ii;
            const size_t row = (size_t)(m0 + ib * 64 + ty * 4 + ii);
            float* crow = C + row * (size_t)Ncol;
#pragma unroll
            for (int jb = 0; jb < 2; ++jb) {
                const int col0 = n0 + jb * 64 + tx * 4;
                float4 v;
                v.x = acc[i][jb * 4 + 0];
                v.y = acc[i][jb * 4 + 1];
                v.z = acc[i][jb * 4 + 2];
                v.w = acc[i][jb * 4 + 3];
                if (EPI == 1) {
                    v.x = tanhf(v.x + bias[col0 + 0]);
                    v.y = tanhf(v.y + bias[col0 + 1]);
                    v.z = tanhf(v.z + bias[col0 + 2]);
                    v.w = tanhf(v.w + bias[col0 + 3]);
                } else if (EPI == 2) {
                    v.x = 1.f / (1.f + __expf(-v.x));
                    v.y = 1.f / (1.f + __expf(-v.y));
                    v.z = 1.f / (1.f + __expf(-v.z));
                    v.w = 1.f / (1.f + __expf(-v.w));
                }
                *(float4*)(crow + col0) = v;
            }
        }
    }
}

__global__ __launch_bounds__(256)
void softmax_mul_f32(float* buf, const float* __restrict__ U, int Ncols)
{
    __shared__ float srow[8192];
    __shared__ float sred[8];
    const int t = threadIdx.x;
    const size_t base = (size_t)blockIdx.x * Ncols;

    float lmax = -3.402823466e38f;
    for (int c = t * 4; c < Ncols; c += 1024) {
        float4 v = *(const float4*)(buf + base + c);
        *(float4*)&srow[c] = v;
        lmax = fmaxf(lmax, fmaxf(fmaxf(v.x, v.y), fmaxf(v.z, v.w)));
    }
    const float rmax = blockReduceMax(lmax, sred);

    float lsum = 0.f;
    for (int c = t * 4; c < Ncols; c += 1024) {
        float4 v = *(float4*)&srow[c];
        v.x = __expf(v.x - rmax);
        v.y = __expf(v.y - rmax);
        v.z = __expf(v.z - rmax);
        v.w = __expf(v.w - rmax);
        *(float4*)&srow[c] = v;
        lsum += v.x + v.y + v.z + v.w;
    }
    const float rsum = blockReduceSum(lsum, sred);
    const float inv = 1.f / rsum;

    for (int c = t * 4; c < Ncols; c += 1024) {
        float4 e = *(float4*)&srow[c];
        float4 u = *(const float4*)(U + base + c);
        float4 o;
        o.x = u.x * e.x * inv;
        o.y = u.y * e.y * inv;
        o.z = u.z * e.z * inv;
        o.w = u.w * e.w * inv;
        *(float4*)(buf + base + c) = o;
    }
}

// ---------------------------------------------------------------- launch
extern "C" void kernel_launch(void* const* d_in, const int* in_sizes, int n_in,
                              void* d_out, int out_size, void* d_ws, size_t ws_size,
                              hipStream_t stream)
{
    const float* U  = (const float*)d_in[0];
    const float* X  = (const float*)d_in[1];
    const float* H1 = (const float*)d_in[2];
    const float* W0 = (const float*)d_in[3];
    const float* W1 = (const float*)d_in[4];
    const float* Wa = (const float*)d_in[5];
    const float* ba = (const float*)d_in[6];
    const int D = in_sizes[6];
    const int N = (int)((long long)in_sizes[2] / D);
    const size_t NN = (size_t)N * N, ND = (size_t)N * D;

    float* Xp = (float*)d_out;          // [N,N] final; scratch for L
    float* Zp = Xp + NN;                // [N,D] final Z; scratch for T

    // ---- workspace layout (slim buffers first, then 2 or 3 NN pools)
    char* p = (char*)d_ws;
    auto alloc = [&](size_t bytes) { char* r = p; p += (bytes + 255) & ~(size_t)255; return r; };
    unsigned short* wa_h  = (unsigned short*)alloc(ND * 2);
    unsigned short* h1_h  = (unsigned short*)alloc(ND * 2);
    unsigned short* k_hi  = (unsigned short*)alloc(ND * 2);
    unsigned short* k_lo  = (unsigned short*)alloc(ND * 2);
    unsigned short* w0t_h = (unsigned short*)alloc(ND * 2);
    unsigned short* vbt   = (unsigned short*)alloc(ND * 2);   // centered XW0^T bf16
    unsigned short* zt_h  = (unsigned short*)alloc(ND * 2);
    unsigned short* uz_h  = (unsigned short*)alloc(ND * 2);
    unsigned short* w1t_h = (unsigned short*)alloc(ND * 2);
    float*          xw0f  = (float*)alloc(ND * 4);
    float*          cvec  = (float*)alloc((size_t)D * 4);
    float*          rsum  = (float*)alloc((size_t)N * 4);
    unsigned short* P0    = (unsigned short*)alloc(NN * 2);
    unsigned short* P1    = (unsigned short*)alloc(NN * 2);
    const size_t need_small = (size_t)(p - (char*)d_ws);
    unsigned short* P2    = (unsigned short*)alloc(NN * 2);
    const size_t need_big = (size_t)(p - (char*)d_ws);

    dim3 blk(256);

    if (N == 8192 && D == 512 && ws_size >= need_small) {
        const bool bigWs = (ws_size >= need_big);
        const dim3 gSlim(D / 128, N / 64);    // (4,128)
        const dim3 gBig(N / 128, N / 128);    // (64,64)
        const dim3 gT(D / 32, N / 32);        // [N,D] -> [D,N]
        const dim3 gTw1(N / 32, D / 32);      // [D,N] -> [N,D]
        const int cgrid = 4096;
        const unsigned short* nullu = nullptr;
        unsigned short* nullw = nullptr;
        const float* nullf = nullptr;

        // X/A2 pool: big tier keeps U-hi in P0 untouched; small tier reuses P0/P1.
        unsigned short* Uhi = P0;
        unsigned short* Ulo = bigWs ? P1 : P1;           // dies after K-GEMM
        unsigned short* XAhi = bigWs ? P1 : P0;          // X-hi then A2-hi
        unsigned short* XAlo = bigWs ? P2 : P1;          // X-lo then A2-lo

        // U -> fp16 hi/lo
        hipLaunchKernelGGL((convert_split<true, true>), dim3(cgrid), blk, 0, stream, U, Uhi, Ulo, NN);
        hipLaunchKernelGGL((convert_split<false, true>), dim3(512), blk, 0, stream, Wa, wa_h, nullw, ND);
        // K = tanh(U @ Wa^T + ba) -> k_hi/k_lo (fp16)
        hipLaunchKernelGGL((gemm_mfma<2, 2, 1, true>), gSlim, blk, 0, stream,
                           Uhi, Ulo, wa_h, ba, nullf, (float*)nullptr, k_hi, k_lo, N, D, N);
        hipLaunchKernelGGL((convert_split<false, true>), dim3(512), blk, 0, stream, H1, h1_h, nullw, ND);
        // L = K @ H1^T -> Xp (f32)
        hipLaunchKernelGGL((gemm_mfma<4, 2, 0, true>), gBig, blk, 0, stream,
                           k_hi, k_lo, h1_h, nullf, nullf, Xp, nullw, nullw, N, N, D);
        // X -> fp16 hi/lo
        hipLaunchKernelGGL((convert_split<true, true>), dim3(cgrid), blk, 0, stream, X, XAhi, XAlo, NN);
        hipLaunchKernelGGL((transpose_cvt<false, true>), gT, blk, 0, stream, W0, w0t_h, nullf, N, D);
        // XW0 = X @ W0 -> xw0f (f32)
        hipLaunchKernelGGL((gemm_mfma<2, 2, 0, true>), gSlim, blk, 0, stream,
                           XAhi, XAlo, w0t_h, nullf, nullf, xw0f, nullw, nullw, N, D, N);
        // column means of XW0 -> cvec
        hipMemsetAsync(cvec, 0, (size_t)D * 4, stream);
        hipLaunchKernelGGL(colsum512, dim3(N / 16), blk, 0, stream, xw0f, cvec, N);
        hipLaunchKernelGGL(scale_vec, dim3(1), dim3(512), 0, stream, cvec, 1.0f / (float)N, D);
        // V = (XW0 - c)^T -> bf16 [D][N]
        hipLaunchKernelGGL((transpose_cvt<true, false>), gT, blk, 0, stream, xw0f, vbt, cvec, N, D);
        // A2 = U * softmax(L) -> bf16 hi/lo + rowsum (overwrites X pool)
        hipLaunchKernelGGL(softmax_mul_hilo, dim3(N), blk, 0, stream, Xp, U, XAhi, XAlo, rsum, N);
        // T = A2 @ V + rsum (x) c -> Zp (bf16 split-2 + rank-1)
        hipLaunchKernelGGL((gemm_mfma<2, 2, 4, false>), gSlim, blk, 0, stream,
                           XAhi, XAlo, vbt, cvec, rsum, Zp, nullw, nullw, N, D, N);
        // Z = softmax_rows(T) in place
        hipLaunchKernelGGL(softmax_inplace_small, dim3(N), blk, 0, stream, Zp, D);
        hipLaunchKernelGGL((transpose_cvt<false, true>), gT, blk, 0, stream, Zp, zt_h, nullf, N, D);
        if (!bigWs) {
            // re-create U-hi fp16 (A2 pool is dead now)
            hipLaunchKernelGGL((convert_split<false, true>), dim3(cgrid), blk, 0, stream, U, Uhi, nullw, NN);
        }
        // UZ = U @ Z -> uz_h (fp16 single)
        hipLaunchKernelGGL((gemm_mfma<2, 1, 3, true>), gSlim, blk, 0, stream,
                           Uhi, nullu, zt_h, nullf, nullf, (float*)nullptr, uz_h, nullw, N, D, N);
        hipLaunchKernelGGL((transpose_cvt<false, true>), gTw1, blk, 0, stream, W1, w1t_h, nullf, D, N);
        // Xp = sigmoid(UZ @ W1) (fp16 single)
        hipLaunchKernelGGL((gemm_mfma<4, 1, 2, true>), gBig, blk, 0, stream,
                           uz_h, nullu, w1t_h, nullf, nullf, Xp, nullw, nullw, N, N, D);
    } else {
        // -------- fp32 fallback
        float* bufA = (float*)d_ws;   // [N,D]
        dim3 gD(D / 128, N / 128);
        dim3 gN(N / 128, N / 128);
        hipLaunchKernelGGL((gemm_f32<1, true>),  gD, blk, 0, stream, U,    Wa, ba,      bufA, N, D, N);
        hipLaunchKernelGGL((gemm_f32<0, true>),  gN, blk, 0, stream, bufA, H1, nullptr, Xp,   N, N, D);
        hipLaunchKernelGGL(softmax_mul_f32, dim3(N), blk, 0, stream, Xp, U, N);
        hipLaunchKernelGGL((gemm_f32<0, false>), gD, blk, 0, stream, X,    W0, nullptr, bufA, N, D, N);
        hipLaunchKernelGGL((gemm_f32<0, false>), gD, blk, 0, stream, Xp,   bufA, nullptr, Zp, N, D, N);
        hipLaunchKernelGGL(softmax_inplace_small, dim3(N), blk, 0, stream, Zp, D);
        hipLaunchKernelGGL((gemm_f32<0, false>), gD, blk, 0, stream, U,    Zp, nullptr, bufA, N, D, N);
        hipLaunchKernelGGL((gemm_f32<2, false>), gN, blk, 0, stream, bufA, W1, nullptr, Xp,  N, N, D);
    }
}